// Round 3
// baseline (253.140 us; speedup 1.0000x reference)
//
#include <hip/hip_runtime.h>
#include <hip/hip_bf16.h>

typedef unsigned int u32;
typedef unsigned short u16;

#define TOKENS 512
#define OUT_F  8192
#define IN_F   4096
#define KPACK  (IN_F / 4)   // packed dwords per weight row (4 codes in low byte of each)

#define TM 128
#define TN 64
#define BK 64

typedef __attribute__((ext_vector_type(8))) short bf16x8;
typedef __attribute__((ext_vector_type(4))) float f32x4;

__device__ __forceinline__ u32 pack_bf16x2(float a, float b) {
    __hip_bfloat162 h = __float22bfloat162_rn(make_float2(a, b));
    union { __hip_bfloat162 h2; u32 u; } cvt;
    cvt.h2 = h;
    return cvt.u;
}

// Decode 4 two-bit codes (low byte of w) -> two dwords of packed bf16.
// code 2 -> +1 (0x3F80), code 0 -> -1 (0xBF80), codes 1/3 -> (-)0.0.
__device__ __forceinline__ void decode4(u32 w, u32& lo, u32& hi) {
    u32 t = (w & 0xFFu) * 0x4001u;   // codes 0,1 at bit pairs [1:0],[17:16]
    u32 u = t >> 4;                  // codes 2,3 at bit pairs [1:0],[17:16]
    u32 nt = ~t;
    u32 nu = ~u;
    lo = ((nt & 0x10001u) * 0x3F80u) | ((nt & 0x20002u) << 14);
    hi = ((nu & 0x10001u) * 0x3F80u) | ((nu & 0x20002u) << 14);
}

// ---- pre-pass: X fp32 -> bf16 into workspace ----
__global__ __launch_bounds__(256) void convert_x(const float* __restrict__ X,
                                                 u16* __restrict__ Xb) {
    int i = (blockIdx.x * 256 + threadIdx.x) * 8;
    float4 a = *(const float4*)(X + i);
    float4 b = *(const float4*)(X + i + 4);
    uint4 q;
    q.x = pack_bf16x2(a.x, a.y);
    q.y = pack_bf16x2(a.z, a.w);
    q.z = pack_bf16x2(b.x, b.y);
    q.w = pack_bf16x2(b.z, b.w);
    *(uint4*)(Xb + i) = q;
}

template <bool PRE>
__global__ __launch_bounds__(256, 2) void ternary_gemm(
    const float* __restrict__ Xf,          // [TOKENS, IN_F] fp32 (used if !PRE)
    const u16* __restrict__ Xb,            // [TOKENS, IN_F] bf16 bits (used if PRE)
    const u32* __restrict__ W2,            // [OUT_F, KPACK]
    const float* __restrict__ alpha,
    const float* __restrict__ bias,
    float* __restrict__ Out)               // [TOKENS, OUT_F] fp32
{
    __shared__ uint2 LUT[256];             // byte -> 4 packed bf16 (8 B)

    const int tid  = threadIdx.x;
    const int lane = tid & 63;
    const int wave = tid >> 6;
    const int quad = lane >> 4;
    const int lr   = lane & 15;

    {
        u32 lo, hi;
        decode4((u32)tid, lo, hi);
        LUT[tid] = make_uint2(lo, hi);
    }
    __syncthreads();   // the ONLY barrier; K-loop below is barrier-free

    const int n0 = blockIdx.x * TN;
    const int m0 = blockIdx.y * TM;
    const int wm = (wave >> 1) * 64;       // 2x2 wave grid, each wave 64x32 of C
    const int wn = (wave & 1) * 32;

    f32x4 acc[4][2];
#pragma unroll
    for (int i = 0; i < 4; ++i)
#pragma unroll
        for (int j = 0; j < 2; ++j)
            acc[i][j] = (f32x4){0.f, 0.f, 0.f, 0.f};

    // ---- per-wave fragment loaders (global -> registers, no LDS) ----
    auto load_a = [&](int ks, bf16x8* af) {
#pragma unroll
        for (int mt = 0; mt < 4; ++mt) {
            int row = m0 + wm + mt * 16 + lr;
#pragma unroll
            for (int kk = 0; kk < 2; ++kk) {
                int k = ks + kk * 32 + quad * 8;
                if (PRE) {
                    af[mt * 2 + kk] = *(const bf16x8*)(Xb + (size_t)row * IN_F + k);
                } else {
                    const float* p = Xf + (size_t)row * IN_F + k;
                    float4 fa = *(const float4*)p;
                    float4 fb = *(const float4*)(p + 4);
                    union { bf16x8 v; u32 u[4]; } c;
                    c.u[0] = pack_bf16x2(fa.x, fa.y);
                    c.u[1] = pack_bf16x2(fa.z, fa.w);
                    c.u[2] = pack_bf16x2(fb.x, fb.y);
                    c.u[3] = pack_bf16x2(fb.z, fb.w);
                    af[mt * 2 + kk] = c.v;
                }
            }
        }
    };

    auto load_b = [&](int ks, uint2* br) {   // br[nt*2+kk]: 2 packed dwords = 8 codes
#pragma unroll
        for (int nt = 0; nt < 2; ++nt) {
            const u32* rp = W2 + (size_t)(n0 + wn + nt * 16 + lr) * KPACK
                               + (ks >> 2) + quad * 2;
            br[nt * 2 + 0] = *(const uint2*)(rp);
            br[nt * 2 + 1] = *(const uint2*)(rp + 8);
        }
    };

    auto compute = [&](const bf16x8* af, const uint2* br) {
#pragma unroll
        for (int nt = 0; nt < 2; ++nt) {
#pragma unroll
            for (int kk = 0; kk < 2; ++kk) {
                uint2 g = br[nt * 2 + kk];
                union { bf16x8 v; uint2 u[2]; } bf;
                bf.u[0] = LUT[g.x & 0xFFu];
                bf.u[1] = LUT[g.y & 0xFFu];
#pragma unroll
                for (int mt = 0; mt < 4; ++mt)
                    acc[mt][nt] = __builtin_amdgcn_mfma_f32_16x16x32_bf16(
                        af[mt * 2 + kk], bf.v, acc[mt][nt], 0, 0, 0);
            }
        }
    };

    // ---- barrier-free K-loop, ping-pong register prefetch ----
    bf16x8 afA[8], afB[8];
    uint2  brA[4], brB[4];

    load_a(0, afA);
    load_b(0, brA);

    for (int ks = 0; ks < IN_F; ks += 2 * BK) {
        load_a(ks + BK, afB);              // ks+BK <= 4032 always valid
        load_b(ks + BK, brB);
        compute(afA, brA);
        if (ks + 2 * BK < IN_F) {
            load_a(ks + 2 * BK, afA);
            load_b(ks + 2 * BK, brA);
        }
        compute(afB, brB);
    }

    // ---- epilogue: alpha * acc + bias, store fp32 ----
#pragma unroll
    for (int nt = 0; nt < 2; ++nt) {
        int ncol = n0 + wn + nt * 16 + lr;
        float av = alpha[ncol];
        float bv = bias[ncol];
#pragma unroll
        for (int mt = 0; mt < 4; ++mt) {
            int mbase = m0 + wm + mt * 16 + quad * 4;
#pragma unroll
            for (int r = 0; r < 4; ++r) {
                Out[(size_t)(mbase + r) * OUT_F + ncol] = acc[mt][nt][r] * av + bv;
            }
        }
    }
}

extern "C" void kernel_launch(void* const* d_in, const int* in_sizes, int n_in,
                              void* d_out, int out_size, void* d_ws, size_t ws_size,
                              hipStream_t stream) {
    const float* x = (const float*)d_in[0];
    const u32* w2 = (const u32*)d_in[1];
    const float* alpha = (const float*)d_in[2];
    const float* bias  = (const float*)d_in[3];
    float* out = (float*)d_out;

    dim3 grid(OUT_F / TN, TOKENS / TM);    // 128 x 4 = 512 blocks, 2 per CU

    const size_t need = (size_t)TOKENS * IN_F * sizeof(u16);
    if (ws_size >= need) {
        u16* xb = (u16*)d_ws;
        convert_x<<<(TOKENS * IN_F) / (256 * 8), 256, 0, stream>>>(x, xb);
        ternary_gemm<true><<<grid, 256, 0, stream>>>(x, xb, w2, alpha, bias, out);
    } else {
        ternary_gemm<false><<<grid, 256, 0, stream>>>(x, nullptr, w2, alpha, bias, out);
    }
}

// Round 4
// 147.264 us; speedup vs baseline: 1.7190x; 1.7190x over previous
//
#include <hip/hip_runtime.h>
#include <hip/hip_bf16.h>

typedef unsigned int u32;
typedef unsigned short u16;

#define TOKENS 512
#define OUT_F  8192
#define IN_F   4096
#define KPACK  (IN_F / 4)   // packed dwords per weight row (4 codes in low byte of each)

#define TM 128
#define TN 64
#define BK 64
#define NSTEP (IN_F / BK)   // 64

typedef __attribute__((ext_vector_type(8))) short bf16x8;
typedef __attribute__((ext_vector_type(4))) float f32x4;

__device__ __forceinline__ u32 pack_bf16x2(float a, float b) {
    __hip_bfloat162 h = __float22bfloat162_rn(make_float2(a, b));
    union { __hip_bfloat162 h2; u32 u; } cvt;
    cvt.h2 = h;
    return cvt.u;
}

// Decode 4 two-bit codes (low byte of w) -> two dwords of packed bf16.
// code 2 -> +1 (0x3F80), code 0 -> -1 (0xBF80), codes 1/3 -> (-)0.0.
__device__ __forceinline__ void decode4(u32 w, u32& lo, u32& hi) {
    u32 t = (w & 0xFFu) * 0x4001u;   // codes 0,1 at bit pairs [1:0],[17:16]
    u32 u = t >> 4;                  // codes 2,3 at bit pairs [1:0],[17:16]
    u32 nt = ~t;
    u32 nu = ~u;
    lo = ((nt & 0x10001u) * 0x3F80u) | ((nt & 0x20002u) << 14);
    hi = ((nu & 0x10001u) * 0x3F80u) | ((nu & 0x20002u) << 14);
}

// async global->LDS DMA, 16B per lane; LDS dest = base + lane*16 (wave-uniform base)
__device__ __forceinline__ void async_ld16(const void* g, void* l) {
    __builtin_amdgcn_global_load_lds(
        (const __attribute__((address_space(1))) u32*)g,
        (__attribute__((address_space(3))) u32*)l, 16, 0, 0);
}

// ---- pre-pass: X fp32 -> bf16 into workspace ----
__global__ __launch_bounds__(256) void convert_x(const float* __restrict__ X,
                                                 u16* __restrict__ Xb) {
    int i = (blockIdx.x * 256 + threadIdx.x) * 8;
    float4 a = *(const float4*)(X + i);
    float4 b = *(const float4*)(X + i + 4);
    uint4 q;
    q.x = pack_bf16x2(a.x, a.y);
    q.y = pack_bf16x2(a.z, a.w);
    q.z = pack_bf16x2(b.x, b.y);
    q.w = pack_bf16x2(b.z, b.w);
    *(uint4*)(Xb + i) = q;
}

// LDS layout (both tiles): row-major rows of BK bf16 (128 B = 8 chunks of 16 B).
// Data k-chunk c of row r lives at slot s = c ^ (r & 7)  (XOR swizzle, involution).
// -> frag ds_read_b128 and stage writes are 2-way bank conflicts (free).

template <bool PRE>
__global__ __launch_bounds__(256, 2) void ternary_gemm(
    const float* __restrict__ Xf,          // [TOKENS, IN_F] fp32 (used if !PRE)
    const u16* __restrict__ Xb,            // [TOKENS, IN_F] bf16 bits (used if PRE)
    const u32* __restrict__ W2,            // [OUT_F, KPACK]
    const float* __restrict__ alpha,
    const float* __restrict__ bias,
    float* __restrict__ Out)               // [TOKENS, OUT_F] fp32
{
    __shared__ u16 As[2][TM * BK];         // 2 x 16 KB
    __shared__ u16 Bs[2][TN * BK];         // 2 x 8 KB   (total 48 KB)

    const int tid  = threadIdx.x;
    const int lane = tid & 63;
    const int wave = tid >> 6;
    const int quad = lane >> 4;
    const int lr   = lane & 15;

    const int n0 = blockIdx.x * TN;
    const int m0 = blockIdx.y * TM;

    // 2x2 wave grid: each wave owns a 64x32 sub-tile of C
    const int wm = (wave >> 1) * 64;
    const int wn = (wave & 1) * 32;

    f32x4 acc[4][2];
#pragma unroll
    for (int i = 0; i < 4; ++i)
#pragma unroll
        for (int j = 0; j < 2; ++j)
            acc[i][j] = (f32x4){0.f, 0.f, 0.f, 0.f};

    // ---- B staging assignment: thread t -> row brow, slot pair (2h, 2h+1) ----
    const int brow = tid >> 2;             // 0..63
    const int h    = tid & 3;              // 0..3
    const int bp   = brow & 7;
    const int be   = (2 * h) ^ (bp & 6);   // even data-chunk index of this thread's pair
    const u32* w2row = W2 + (size_t)(n0 + brow) * KPACK + be * 2;

    auto load_w2 = [&](int ks) -> uint4 {
        return *(const uint4*)(w2row + (ks >> 2));
    };

    auto stage_b = [&](const uint4& w, int buf) {
        u32 a0, a1, b0, b1, c0, c1, d0, d1;
        decode4(w.x, a0, a1);
        decode4(w.y, b0, b1);
        decode4(w.z, c0, c1);
        decode4(w.w, d0, d1);
        uint4 qa = {a0, a1, b0, b1};       // data chunk be   (8 consecutive k)
        uint4 qb = {c0, c1, d0, d1};       // data chunk be+1
        int po = bp & 1;
        *(uint4*)&Bs[buf][brow * BK + (2 * h + po) * 8]       = qa;  // slot = chunk ^ p
        *(uint4*)&Bs[buf][brow * BK + (2 * h + (po ^ 1)) * 8] = qb;
    };

    // ---- A staging ----
    auto stage_a_dma = [&](int ks, int buf) {
#pragma unroll
        for (int i = 0; i < 4; ++i) {
            int rbase = wave * 32 + i * 8;          // 8 rows per wave-inst
            int row = rbase + (lane >> 3);
            int c = (lane & 7) ^ (row & 7);         // data chunk for slot (lane&7)
            const u16* g = Xb + (size_t)(m0 + row) * IN_F + ks + c * 8;
            async_ld16(g, &As[buf][rbase * BK]);    // lane writes base + lane*16
        }
    };

    auto stage_a_f32 = [&](int ks, int buf) {
#pragma unroll
        for (int i = 0; i < 4; ++i) {
            int id = i * 256 + tid;
            int row = id >> 3, s = id & 7;
            int c = s ^ (row & 7);
            const float* p = Xf + (size_t)(m0 + row) * IN_F + ks + c * 8;
            float4 fa = *(const float4*)p;
            float4 fb = *(const float4*)(p + 4);
            uint4 q;
            q.x = pack_bf16x2(fa.x, fa.y);
            q.y = pack_bf16x2(fa.z, fa.w);
            q.z = pack_bf16x2(fb.x, fb.y);
            q.w = pack_bf16x2(fb.z, fb.w);
            *(uint4*)&As[buf][row * BK + s * 8] = q;
        }
    };

    auto compute = [&](int buf) {
        bf16x8 af[4][2], bfv[2][2];
#pragma unroll
        for (int kk = 0; kk < 2; ++kk) {
            int s = (kk * 4 + quad) ^ (lr & 7);     // swizzled chunk slot
#pragma unroll
            for (int mt = 0; mt < 4; ++mt)
                af[mt][kk] = *(const bf16x8*)&As[buf][(wm + mt * 16 + lr) * BK + s * 8];
#pragma unroll
            for (int nt = 0; nt < 2; ++nt)
                bfv[nt][kk] = *(const bf16x8*)&Bs[buf][(wn + nt * 16 + lr) * BK + s * 8];
        }
#pragma unroll
        for (int kk = 0; kk < 2; ++kk)
#pragma unroll
            for (int mt = 0; mt < 4; ++mt)
#pragma unroll
                for (int nt = 0; nt < 2; ++nt)
                    acc[mt][nt] = __builtin_amdgcn_mfma_f32_16x16x32_bf16(
                        af[mt][kk], bfv[nt][kk], acc[mt][nt], 0, 0, 0);
    };

    // ---- prologue: stage step 0, prefetch W2 for step 1 ----
    uint4 wcur = load_w2(0);
    if (PRE) stage_a_dma(0, 0); else stage_a_f32(0, 0);
    stage_b(wcur, 0);
    uint4 wnext = load_w2(BK);
    __syncthreads();

    // ---- main loop: one barrier per step; new loads issued right AFTER the
    //      barrier so the structural vmcnt(0)-before-barrier drain sees them
    //      with a full compute phase in flight ----
    for (int s = 0; s < NSTEP; ++s) {
        int buf = s & 1;
        if (s + 1 < NSTEP) {
            if (PRE) stage_a_dma((s + 1) * BK, buf ^ 1);
            else     stage_a_f32((s + 1) * BK, buf ^ 1);
            stage_b(wnext, buf ^ 1);               // wnext landed (drained at prev barrier)
        }
        if (s + 2 < NSTEP) wnext = load_w2((s + 2) * BK);
        compute(buf);
        __syncthreads();
    }

    // ---- epilogue: alpha * acc + bias, store fp32 ----
#pragma unroll
    for (int nt = 0; nt < 2; ++nt) {
        int ncol = n0 + wn + nt * 16 + lr;
        float av = alpha[ncol];
        float bv = bias[ncol];
#pragma unroll
        for (int mt = 0; mt < 4; ++mt) {
            int mbase = m0 + wm + mt * 16 + quad * 4;
#pragma unroll
            for (int r = 0; r < 4; ++r) {
                Out[(size_t)(mbase + r) * OUT_F + ncol] = acc[mt][nt][r] * av + bv;
            }
        }
    }
}

extern "C" void kernel_launch(void* const* d_in, const int* in_sizes, int n_in,
                              void* d_out, int out_size, void* d_ws, size_t ws_size,
                              hipStream_t stream) {
    const float* x = (const float*)d_in[0];
    const u32* w2 = (const u32*)d_in[1];
    const float* alpha = (const float*)d_in[2];
    const float* bias  = (const float*)d_in[3];
    float* out = (float*)d_out;

    dim3 grid(OUT_F / TN, TOKENS / TM);    // 128 x 4 = 512 blocks, 2 per CU

    const size_t need = (size_t)TOKENS * IN_F * sizeof(u16);
    if (ws_size >= need) {
        u16* xb = (u16*)d_ws;
        convert_x<<<(TOKENS * IN_F) / (256 * 8), 256, 0, stream>>>(x, xb);
        ternary_gemm<true><<<grid, 256, 0, stream>>>(x, xb, w2, alpha, bias, out);
    } else {
        ternary_gemm<false><<<grid, 256, 0, stream>>>(x, nullptr, w2, alpha, bias, out);
    }
}

// Round 5
// 144.056 us; speedup vs baseline: 1.7572x; 1.0223x over previous
//
#include <hip/hip_runtime.h>
#include <hip/hip_bf16.h>

typedef unsigned int u32;
typedef unsigned short u16;

#define TOKENS 512
#define OUT_F  8192
#define IN_F   4096
#define KPACK  (IN_F / 4)   // packed dwords per W2 row (4 codes in low byte of each)

#define TM 128
#define TN 64
#define BK 64
#define NSTEP (IN_F / BK)   // 64

typedef __attribute__((ext_vector_type(8))) short bf16x8;
typedef __attribute__((ext_vector_type(4))) float f32x4;

__device__ __forceinline__ u32 pack_bf16x2(float a, float b) {
    __hip_bfloat162 h = __float22bfloat162_rn(make_float2(a, b));
    union { __hip_bfloat162 h2; u32 u; } cvt;
    cvt.h2 = h;
    return cvt.u;
}

// Decode 4 two-bit codes (low byte of w) -> two dwords of packed bf16.
// code 2 -> +1 (0x3F80), code 0 -> -1 (0xBF80), codes 1/3 -> (-)0.0.
__device__ __forceinline__ void decode4(u32 w, u32& lo, u32& hi) {
    u32 t = (w & 0xFFu) * 0x4001u;
    u32 u = t >> 4;
    u32 nt = ~t;
    u32 nu = ~u;
    lo = ((nt & 0x10001u) * 0x3F80u) | ((nt & 0x20002u) << 14);
    hi = ((nu & 0x10001u) * 0x3F80u) | ((nu & 0x20002u) << 14);
}

// 16 bits = 2 dense bytes = 8 codes (8 consecutive k) -> one B fragment.
__device__ __forceinline__ bf16x8 decode_frag(u32 hw) {
    u32 d0, d1, d2, d3;
    decode4(hw, d0, d1);
    decode4(hw >> 8, d2, d3);
    union { bf16x8 v; u32 u[4]; } c;
    c.u[0] = d0; c.u[1] = d1; c.u[2] = d2; c.u[3] = d3;
    return c.v;
}

// async global->LDS DMA, 16B per lane; LDS dest = base + lane*16 (wave-uniform base)
__device__ __forceinline__ void async_ld16(const void* g, void* l) {
    __builtin_amdgcn_global_load_lds(
        (const __attribute__((address_space(1))) u32*)g,
        (__attribute__((address_space(3))) u32*)l, 16, 0, 0);
}

// ---- pre-pass 1: X fp32 -> bf16 ----
__global__ __launch_bounds__(256) void convert_x(const float* __restrict__ X,
                                                 u16* __restrict__ Xb) {
    int i = (blockIdx.x * 256 + threadIdx.x) * 8;
    float4 a = *(const float4*)(X + i);
    float4 b = *(const float4*)(X + i + 4);
    uint4 q;
    q.x = pack_bf16x2(a.x, a.y);
    q.y = pack_bf16x2(a.z, a.w);
    q.z = pack_bf16x2(b.x, b.y);
    q.w = pack_bf16x2(b.z, b.w);
    *(uint4*)(Xb + i) = q;
}

// ---- pre-pass 2: repack W2 -> dense 2-bit, fragment-major ----
// W4[(ng32*NSTEP + S)*64 + lane] : uint2
//   .x = codes for o = ng32*32 +      (lane&15):  bits[15:0] k=S*64+quad*8..+7,
//                                                 bits[31:16] k=+32
//   .y = same for o = ng32*32 + 16 + (lane&15)
__global__ __launch_bounds__(256) void repack_w(const u32* __restrict__ W2,
                                                uint2* __restrict__ W4) {
    __shared__ u32 staged[32 * 256];   // dense bytes: row r, dword d = W2 dwords 4d..4d+3
    const int ng = blockIdx.x;         // 32 output rows per block
    const int t  = threadIdx.x;

    {   // phase 1: gather low bytes, coalesce into dense dwords
        int r = t >> 3, c8 = t & 7;
        size_t base = (size_t)(ng * 32 + r) * KPACK + c8 * 128;
#pragma unroll
        for (int i = 0; i < 32; ++i) {
            uint4 w = *(const uint4*)(W2 + base + 4 * i);
            staged[r * 256 + c8 * 32 + i] =
                (w.x & 0xFFu) | ((w.y & 0xFFu) << 8) |
                ((w.z & 0xFFu) << 16) | ((w.w & 0xFFu) << 24);
        }
    }
    __syncthreads();
    {   // phase 2: emit fragment-major uint2s (coalesced)
        const u16* sp = (const u16*)staged;   // row r at u16 index r*512
#pragma unroll
        for (int j = 0; j < 16; ++j) {
            int u = t + 256 * j;
            int S = u >> 6, l = u & 63;
            int lr = l & 15, quad = l >> 4;
            u32 lo0 = sp[lr * 512 + S * 8 + quad];
            u32 hi0 = sp[lr * 512 + S * 8 + 4 + quad];
            u32 lo1 = sp[(lr + 16) * 512 + S * 8 + quad];
            u32 hi1 = sp[(lr + 16) * 512 + S * 8 + 4 + quad];
            uint2 o;
            o.x = lo0 | (hi0 << 16);
            o.y = lo1 | (hi1 << 16);
            W4[((size_t)ng * NSTEP + S) * 64 + l] = o;
        }
    }
}

// LDS A layout: rows of BK bf16 (8 chunks of 16B); data chunk c of row r at
// slot c ^ (r&7) (XOR swizzle; conflict-free, DMA-compatible; verified R4).

template <bool PRE, bool PACKED>
__global__ __launch_bounds__(256, 4) void ternary_gemm(
    const float* __restrict__ Xf,
    const u16* __restrict__ Xb,
    const u32* __restrict__ W2,
    const uint2* __restrict__ W4,
    const float* __restrict__ alpha,
    const float* __restrict__ bias,
    float* __restrict__ Out)
{
    __shared__ u16 As[2][TM * BK];     // 2 x 16 KB, A only

    const int tid  = threadIdx.x;
    const int lane = tid & 63;
    const int wave = tid >> 6;
    const int quad = lane >> 4;
    const int lr   = lane & 15;

    const int n0 = blockIdx.x * TN;
    const int m0 = blockIdx.y * TM;
    const int wm = (wave >> 1) * 64;   // 2x2 wave grid: 64x32 C sub-tile per wave
    const int wn = (wave & 1) * 32;
    const int ng32 = (n0 + wn) >> 5;   // this wave's 32-col group

    f32x4 acc[4][2];
#pragma unroll
    for (int i = 0; i < 4; ++i)
#pragma unroll
        for (int j = 0; j < 2; ++j)
            acc[i][j] = (f32x4){0.f, 0.f, 0.f, 0.f};

    auto stage_a_dma = [&](int ks, int buf) {
#pragma unroll
        for (int i = 0; i < 4; ++i) {
            int rbase = wave * 32 + i * 8;
            int row = rbase + (lane >> 3);
            int c = (lane & 7) ^ (row & 7);
            const u16* g = Xb + (size_t)(m0 + row) * IN_F + ks + c * 8;
            async_ld16(g, &As[buf][rbase * BK]);
        }
    };

    auto stage_a_f32 = [&](int ks, int buf) {
#pragma unroll
        for (int i = 0; i < 4; ++i) {
            int id = i * 256 + tid;
            int row = id >> 3, s = id & 7;
            int c = s ^ (row & 7);
            const float* p = Xf + (size_t)(m0 + row) * IN_F + ks + c * 8;
            float4 fa = *(const float4*)p;
            float4 fb = *(const float4*)(p + 4);
            uint4 q;
            q.x = pack_bf16x2(fa.x, fa.y);
            q.y = pack_bf16x2(fa.z, fa.w);
            q.z = pack_bf16x2(fb.x, fb.y);
            q.w = pack_bf16x2(fb.z, fb.w);
            *(uint4*)&As[buf][row * BK + s * 8] = q;
        }
    };

    // B codes for step s in W4 format (works for both sources)
    auto load_w = [&](int s) -> uint2 {
        if (PACKED) {
            return W4[((size_t)ng32 * NSTEP + s) * 64 + lane];
        } else {
            const u32* r0 = W2 + (size_t)(n0 + wn + lr) * KPACK + s * 16 + quad * 2;
            const u32* r1 = W2 + (size_t)(n0 + wn + 16 + lr) * KPACK + s * 16 + quad * 2;
            uint2 a0 = *(const uint2*)r0, b0 = *(const uint2*)(r0 + 8);
            uint2 a1 = *(const uint2*)r1, b1 = *(const uint2*)(r1 + 8);
            uint2 w;
            w.x = (a0.x & 0xFFu) | ((a0.y & 0xFFu) << 8) |
                  ((b0.x & 0xFFu) << 16) | ((b0.y & 0xFFu) << 24);
            w.y = (a1.x & 0xFFu) | ((a1.y & 0xFFu) << 8) |
                  ((b1.x & 0xFFu) << 16) | ((b1.y & 0xFFu) << 24);
            return w;
        }
    };

    auto compute = [&](int buf, uint2 wreg) {
#pragma unroll
        for (int kk = 0; kk < 2; ++kk) {
            int sl = (kk * 4 + quad) ^ (lr & 7);
            bf16x8 af[4];
#pragma unroll
            for (int mt = 0; mt < 4; ++mt)
                af[mt] = *(const bf16x8*)&As[buf][(wm + mt * 16 + lr) * BK + sl * 8];
            bf16x8 b0 = decode_frag(kk ? (wreg.x >> 16) : (wreg.x & 0xFFFFu));
            bf16x8 b1 = decode_frag(kk ? (wreg.y >> 16) : (wreg.y & 0xFFFFu));
#pragma unroll
            for (int mt = 0; mt < 4; ++mt) {
                acc[mt][0] = __builtin_amdgcn_mfma_f32_16x16x32_bf16(af[mt], b0, acc[mt][0], 0, 0, 0);
                acc[mt][1] = __builtin_amdgcn_mfma_f32_16x16x32_bf16(af[mt], b1, acc[mt][1], 0, 0, 0);
            }
        }
    };

    // ---- prologue ----
    uint2 wcur = load_w(0);
    uint2 wnext = load_w(1);
    if (PRE) stage_a_dma(0, 0); else stage_a_f32(0, 0);
    __syncthreads();

    // ---- K-loop: one barrier/step; stage + W-prefetch issued right after it ----
    for (int s = 0; s < NSTEP; ++s) {
        int buf = s & 1;
        if (s + 1 < NSTEP) {
            if (PRE) stage_a_dma((s + 1) * BK, buf ^ 1);
            else     stage_a_f32((s + 1) * BK, buf ^ 1);
        }
        uint2 wnn = (s + 2 < NSTEP) ? load_w(s + 2) : make_uint2(0, 0);
        compute(buf, wcur);
        wcur = wnext;
        wnext = wnn;
        __syncthreads();
    }

    // ---- epilogue ----
#pragma unroll
    for (int nt = 0; nt < 2; ++nt) {
        int ncol = n0 + wn + nt * 16 + lr;
        float av = alpha[ncol];
        float bv = bias[ncol];
#pragma unroll
        for (int mt = 0; mt < 4; ++mt) {
            int mbase = m0 + wm + mt * 16 + quad * 4;
#pragma unroll
            for (int r = 0; r < 4; ++r) {
                Out[(size_t)(mbase + r) * OUT_F + ncol] = acc[mt][nt][r] * av + bv;
            }
        }
    }
}

extern "C" void kernel_launch(void* const* d_in, const int* in_sizes, int n_in,
                              void* d_out, int out_size, void* d_ws, size_t ws_size,
                              hipStream_t stream) {
    const float* x = (const float*)d_in[0];
    const u32* w2 = (const u32*)d_in[1];
    const float* alpha = (const float*)d_in[2];
    const float* bias  = (const float*)d_in[3];
    float* out = (float*)d_out;

    dim3 grid(OUT_F / TN, TOKENS / TM);    // 128 x 4 = 512 blocks

    const size_t xb_bytes = (size_t)TOKENS * IN_F * sizeof(u16);       // 4 MB
    const size_t w4_bytes = (size_t)OUT_F * IN_F / 4;                  // 8 MB

    if (ws_size >= xb_bytes + w4_bytes) {
        u16* xb = (u16*)d_ws;
        uint2* w4 = (uint2*)((char*)d_ws + xb_bytes);
        convert_x<<<(TOKENS * IN_F) / (256 * 8), 256, 0, stream>>>(x, xb);
        repack_w<<<OUT_F / 32, 256, 0, stream>>>(w2, w4);
        ternary_gemm<true, true><<<grid, 256, 0, stream>>>(x, xb, w2, w4, alpha, bias, out);
    } else if (ws_size >= xb_bytes) {
        u16* xb = (u16*)d_ws;
        convert_x<<<(TOKENS * IN_F) / (256 * 8), 256, 0, stream>>>(x, xb);
        ternary_gemm<true, false><<<grid, 256, 0, stream>>>(x, xb, w2, nullptr, alpha, bias, out);
    } else {
        ternary_gemm<false, false><<<grid, 256, 0, stream>>>(x, nullptr, w2, nullptr, alpha, bias, out);
    }
}

// Round 6
// 137.617 us; speedup vs baseline: 1.8395x; 1.0468x over previous
//
#include <hip/hip_runtime.h>
#include <hip/hip_bf16.h>

typedef unsigned int u32;
typedef unsigned short u16;

#define TOKENS 512
#define OUT_F  8192
#define IN_F   4096
#define KPACK  (IN_F / 4)
#define NSTEP  64            // K-steps of 64

typedef __attribute__((ext_vector_type(8))) short bf16x8;
typedef __attribute__((ext_vector_type(4))) float f32x4;
typedef __attribute__((ext_vector_type(16))) float f32x16;

__device__ __forceinline__ u32 pack_bf16x2(float a, float b) {
    __hip_bfloat162 h = __float22bfloat162_rn(make_float2(a, b));
    union { __hip_bfloat162 h2; u32 u; } cvt;
    cvt.h2 = h;
    return cvt.u;
}

// Decode 4 two-bit codes (b = one dense byte) -> two dwords of packed bf16.
// code 2 -> +1 (0x3F80), code 0 -> -1 (0xBF80), codes 1/3 -> (-)0.0.
// Full-rate ops only: lshl_add + umul24 (no quarter-rate v_mul_lo_u32).
__device__ __forceinline__ void decode4(u32 b, u32& lo, u32& hi) {
    u32 t = b + (b << 14);           // v_lshl_add_u32
    u32 u = t >> 4;
    u32 nt = ~t, nu = ~u;
    lo = __umul24(nt & 0x10001u, 0x3F80u) | ((nt & 0x20002u) << 14);
    hi = __umul24(nu & 0x10001u, 0x3F80u) | ((nu & 0x20002u) << 14);
}

// 16 bits = 2 dense bytes = 8 consecutive-k codes -> one MFMA B fragment.
__device__ __forceinline__ bf16x8 decode_frag(u32 hw) {
    u32 d0, d1, d2, d3;
    decode4(hw & 0xFFu, d0, d1);
    decode4((hw >> 8) & 0xFFu, d2, d3);
    union { bf16x8 v; u32 u[4]; } c;
    c.u[0] = d0; c.u[1] = d1; c.u[2] = d2; c.u[3] = d3;
    return c.v;
}

__device__ __forceinline__ void async_ld16(const void* g, void* l) {
    __builtin_amdgcn_global_load_lds(
        (const __attribute__((address_space(1))) u32*)g,
        (__attribute__((address_space(3))) u32*)l, 16, 0, 0);
}

// ---- pre-pass 1: X fp32 -> bf16 ----
__global__ __launch_bounds__(256) void convert_x(const float* __restrict__ X,
                                                 u16* __restrict__ Xb) {
    int i = (blockIdx.x * 256 + threadIdx.x) * 8;
    float4 a = *(const float4*)(X + i);
    float4 b = *(const float4*)(X + i + 4);
    uint4 q;
    q.x = pack_bf16x2(a.x, a.y);
    q.y = pack_bf16x2(a.z, a.w);
    q.z = pack_bf16x2(b.x, b.y);
    q.w = pack_bf16x2(b.z, b.w);
    *(uint4*)(Xb + i) = q;
}

// ---- pre-pass 2: repack W2 -> dense 2-bit, fragment-major for the k-split gemm ----
// W6 u32 at index ((ngrp*2+nh)*64 + S)*256/... = (ngrp*2+nh)*16384 + S*256 + kq*64 + lane
//   .u16[nt] = 8 codes for col = ngrp*128 + nh*64 + nt*32 + (lane&31),
//              k = S*64 + kq*16 + (lane>>5)*8 .. +7
__global__ __launch_bounds__(256) void repack_w6(const u32* __restrict__ W2,
                                                 u32* __restrict__ W6) {
    __shared__ u32 staged[128 * 16];   // dense bytes, swizzled: staged[r*16 + (j ^ (r&15))]
    const int ngrp = blockIdx.x;       // 64 groups of 128 cols
    const int kc   = blockIdx.y;       // 16 chunks of 256 k (64 dense dwords... 64 W2-dwords)
    const int t = threadIdx.x;

    {   // phase 1: coalesced uint4 reads, pack low bytes -> dense dwords
        const int c = t & 15;
#pragma unroll
        for (int i = 0; i < 8; ++i) {
            int r = i * 16 + (t >> 4);
            uint4 w = *(const uint4*)(W2 + (size_t)(ngrp * 128 + r) * KPACK + kc * 64 + c * 4);
            staged[r * 16 + (c ^ (r & 15))] =
                (w.x & 0xFFu) | ((w.y & 0xFFu) << 8) | ((w.z & 0xFFu) << 16) | ((w.w & 0xFFu) << 24);
        }
    }
    __syncthreads();
    {   // phase 2: emit fragment-major u32s (coalesced writes)
        const u16* sp = (const u16*)staged;
#pragma unroll
        for (int j = 0; j < 8; ++j) {
            int e = t + 256 * j;                 // 2048 outputs per block
            int lane = e & 63;
            int kq   = (e >> 6) & 3;
            int Sl   = (e >> 8) & 3;
            int nh   = (e >> 10) & 1;
            int hw = Sl * 8 + kq * 2 + (lane >> 5);   // local halfword idx [0,32)
            int r0 = nh * 64 + (lane & 31);
            int r1 = r0 + 32;
            u32 x0 = sp[r0 * 32 + 2 * ((hw >> 1) ^ (r0 & 15)) + (hw & 1)];
            u32 x1 = sp[r1 * 32 + 2 * ((hw >> 1) ^ (r1 & 15)) + (hw & 1)];
            size_t idx = (size_t)(ngrp * 2 + nh) * 16384 + (size_t)(kc * 4 + Sl) * 256
                       + kq * 64 + lane;
            W6[idx] = x0 | (x1 << 16);
        }
    }
}

// ---- main GEMM: 128x128 block, 8 waves = 4 k-quarters x 2 n-halves, 32x32x16 MFMA ----
// LDS A tile: 128 rows x 64 k bf16 (16 KB) double-buffered; 16B chunk c of row r
// stored at slot c ^ (r&7) (XOR swizzle, DMA-compatible, conflict-free — verified R4/R5).
__global__ __launch_bounds__(512, 2) void ternary_gemm_ks(
    const u16* __restrict__ Xb,
    const u32* __restrict__ W6,
    const float* __restrict__ alpha,
    const float* __restrict__ bias,
    float* __restrict__ Out)
{
    __shared__ uint4 smem[4096];       // 64 KB: K-loop uses 32 KB (As[2]); epilogue reuses as red[]
    u16* As = (u16*)smem;

    const int tid  = threadIdx.x;
    const int lane = tid & 63;
    const int wave = tid >> 6;         // 8 waves
    const int kq = wave & 3;           // k-quarter (16 of each 64-k step)
    const int nh = wave >> 2;          // n-half (64 cols)

    const int m0 = blockIdx.x * 128;   // 4 m-groups
    const int n0 = blockIdx.y * 128;   // 64 n-groups
    const int ngrp = blockIdx.y;

    f32x16 acc[4][2];
#pragma unroll
    for (int mt = 0; mt < 4; ++mt)
#pragma unroll
        for (int nt = 0; nt < 2; ++nt)
#pragma unroll
            for (int i = 0; i < 16; ++i)
                acc[mt][nt][i] = 0.f;

    // A fragment LDS offsets (u16 units). row&7 == lane&... (mt*32 ≡ 0 mod 8):
    const int slot = ((kq * 2 + (lane >> 5)) ^ (lane & 7));
    int ofsA[4];
#pragma unroll
    for (int mt = 0; mt < 4; ++mt)
        ofsA[mt] = (mt * 32 + (lane & 31)) * 64 + slot * 8;

    // DMA staging: wave stages rows [wave*16, wave*16+16), 2 insts x 8 rows.
    const int r_l = lane >> 3;
    const int c_l = (lane & 7) ^ r_l;          // data chunk for this lane's slot
    const u16* gA[2];
    u16* lA[2];
#pragma unroll
    for (int i = 0; i < 2; ++i) {
        int rbase = wave * 16 + i * 8;
        gA[i] = Xb + (size_t)(m0 + rbase + r_l) * IN_F + c_l * 8;
        lA[i] = As + rbase * 64;
    }

    // W codes pointer (u32 per lane per step)
    const u32* wp = W6 + (size_t)(ngrp * 2 + nh) * 16384 + kq * 64 + lane;

    u32 wcur = wp[0];
    u32 wnxt = wp[256];
#pragma unroll
    for (int i = 0; i < 2; ++i) async_ld16(gA[i], lA[i]);
    __syncthreads();

    for (int s = 0; s < NSTEP; ++s) {
        const int buf = s & 1;
        if (s + 1 < NSTEP) {
            const int off = (s + 1) * 64;
#pragma unroll
            for (int i = 0; i < 2; ++i)
                async_ld16(gA[i] + off, lA[i] + (buf ^ 1) * 8192);
        }
        u32 wtmp = 0;
        if (s + 2 < NSTEP) wtmp = wp[(size_t)(s + 2) * 256];

        const u16* ab = As + buf * 8192;
        bf16x8 a0 = *(const bf16x8*)(ab + ofsA[0]);
        bf16x8 a1 = *(const bf16x8*)(ab + ofsA[1]);
        bf16x8 a2 = *(const bf16x8*)(ab + ofsA[2]);
        bf16x8 a3 = *(const bf16x8*)(ab + ofsA[3]);
        bf16x8 b0 = decode_frag(wcur & 0xFFFFu);
        bf16x8 b1 = decode_frag(wcur >> 16);

        acc[0][0] = __builtin_amdgcn_mfma_f32_32x32x16_bf16(a0, b0, acc[0][0], 0, 0, 0);
        acc[1][0] = __builtin_amdgcn_mfma_f32_32x32x16_bf16(a1, b0, acc[1][0], 0, 0, 0);
        acc[2][0] = __builtin_amdgcn_mfma_f32_32x32x16_bf16(a2, b0, acc[2][0], 0, 0, 0);
        acc[3][0] = __builtin_amdgcn_mfma_f32_32x32x16_bf16(a3, b0, acc[3][0], 0, 0, 0);
        acc[0][1] = __builtin_amdgcn_mfma_f32_32x32x16_bf16(a0, b1, acc[0][1], 0, 0, 0);
        acc[1][1] = __builtin_amdgcn_mfma_f32_32x32x16_bf16(a1, b1, acc[1][1], 0, 0, 0);
        acc[2][1] = __builtin_amdgcn_mfma_f32_32x32x16_bf16(a2, b1, acc[2][1], 0, 0, 0);
        acc[3][1] = __builtin_amdgcn_mfma_f32_32x32x16_bf16(a3, b1, acc[3][1], 0, 0, 0);

        wcur = wnxt;
        wnxt = wtmp;
        __syncthreads();
    }

    // ---- 4-way k-quarter reduction through LDS (3 rounds, 64 KB scratch) ----
    f32x4* red = (f32x4*)smem;         // [nh][32 idx][64 lanes]
#pragma unroll 1
    for (int q = 1; q < 4; ++q) {
        if (kq == q) {
            f32x4* dst = red + nh * 2048 + lane;
#pragma unroll
            for (int mt = 0; mt < 4; ++mt)
#pragma unroll
                for (int nt = 0; nt < 2; ++nt)
#pragma unroll
                    for (int sub = 0; sub < 4; ++sub) {
                        f32x4 v = {acc[mt][nt][sub * 4 + 0], acc[mt][nt][sub * 4 + 1],
                                   acc[mt][nt][sub * 4 + 2], acc[mt][nt][sub * 4 + 3]};
                        dst[(mt * 8 + nt * 4 + sub) * 64] = v;
                    }
        }
        __syncthreads();
        if (kq == 0) {
            const f32x4* src = red + nh * 2048 + lane;
#pragma unroll
            for (int mt = 0; mt < 4; ++mt)
#pragma unroll
                for (int nt = 0; nt < 2; ++nt)
#pragma unroll
                    for (int sub = 0; sub < 4; ++sub) {
                        f32x4 v = src[(mt * 8 + nt * 4 + sub) * 64];
#pragma unroll
                        for (int i = 0; i < 4; ++i)
                            acc[mt][nt][sub * 4 + i] += v[i];
                    }
        }
        __syncthreads();
    }

    // ---- epilogue (kq==0 waves): alpha*acc + bias ----
    if (kq == 0) {
#pragma unroll
        for (int nt = 0; nt < 2; ++nt) {
            int ncol = n0 + nh * 64 + nt * 32 + (lane & 31);
            float av = alpha[ncol];
            float bv = bias[ncol];
#pragma unroll
            for (int mt = 0; mt < 4; ++mt) {
#pragma unroll
                for (int r = 0; r < 16; ++r) {
                    int row = m0 + mt * 32 + (r & 3) + 8 * (r >> 2) + 4 * (lane >> 5);
                    Out[(size_t)row * OUT_F + ncol] = acc[mt][nt][r] * av + bv;
                }
            }
        }
    }
}

// ---- naive fallback (only if workspace is too small; correctness-only) ----
__global__ void ternary_naive(const float* __restrict__ X, const u32* __restrict__ W2,
                              const float* __restrict__ alpha, const float* __restrict__ bias,
                              float* __restrict__ Out) {
    int o  = blockIdx.x * 64 + (threadIdx.x & 63);
    int tk = blockIdx.y * 4 + (threadIdx.x >> 6);
    const float* x = X + (size_t)tk * IN_F;
    const u32* w = W2 + (size_t)o * KPACK;
    float s = 0.f;
    for (int d = 0; d < KPACK; ++d) {
        u32 b = w[d] & 0xFFu;
        const float* xp = x + d * 4;
#pragma unroll
        for (int j = 0; j < 4; ++j) {
            u32 c = (b >> (2 * j)) & 3u;
            float wv = (c == 2u) ? 1.f : ((c == 0u) ? -1.f : 0.f);
            s += xp[j] * wv;
        }
    }
    Out[(size_t)tk * OUT_F + o] = s * alpha[o] + bias[o];
}

extern "C" void kernel_launch(void* const* d_in, const int* in_sizes, int n_in,
                              void* d_out, int out_size, void* d_ws, size_t ws_size,
                              hipStream_t stream) {
    const float* x = (const float*)d_in[0];
    const u32* w2 = (const u32*)d_in[1];
    const float* alpha = (const float*)d_in[2];
    const float* bias  = (const float*)d_in[3];
    float* out = (float*)d_out;

    const size_t xb_bytes = (size_t)TOKENS * IN_F * sizeof(u16);   // 4 MB
    const size_t w6_bytes = (size_t)OUT_F * IN_F / 4;              // 8 MB

    if (ws_size >= xb_bytes + w6_bytes) {
        u16* xb = (u16*)d_ws;
        u32* w6 = (u32*)((char*)d_ws + xb_bytes);
        convert_x<<<(TOKENS * IN_F) / (256 * 8), 256, 0, stream>>>(x, xb);
        repack_w6<<<dim3(64, 16), 256, 0, stream>>>(w2, w6);
        ternary_gemm_ks<<<dim3(4, 64), 512, 0, stream>>>(xb, w6, alpha, bias, out);
    } else {
        ternary_naive<<<dim3(OUT_F / 64, TOKENS / 4), 256, 0, stream>>>(x, w2, alpha, bias, out);
    }
}

// Round 7
// 131.771 us; speedup vs baseline: 1.9211x; 1.0444x over previous
//
#include <hip/hip_runtime.h>
#include <hip/hip_bf16.h>

typedef unsigned int u32;
typedef unsigned short u16;

#define TOKENS 512
#define OUT_F  8192
#define IN_F   4096
#define KPACK  (IN_F / 4)
#define TM 64
#define TN 128
#define BKW 128              // k per window
#define NWIN (IN_F / BKW)    // 32

typedef __attribute__((ext_vector_type(8))) short bf16x8;
typedef __attribute__((ext_vector_type(4))) float f32x4;
typedef __attribute__((ext_vector_type(16))) float f32x16;

__device__ __forceinline__ u32 pack_bf16x2(float a, float b) {
    __hip_bfloat162 h = __float22bfloat162_rn(make_float2(a, b));
    union { __hip_bfloat162 h2; u32 u; } cvt;
    cvt.h2 = h;
    return cvt.u;
}

// 2 codes (4 bits) -> 2 packed bf16 via byte-table v_perm.
// code 0 -> 0xBF80 (-1), 2 -> 0x3F80 (+1), 1/3 -> 0x0000.
__device__ __forceinline__ u32 decode_pair(u32 d) {
    u32 s = (__umul24(d, 0x808202u) & 0x06060606u) + 0x01000100u;
    return __builtin_amdgcn_perm(0x00003F80u, 0x0000BF80u, s);
}
// 16 bits (8 consecutive-k codes) at bit offset sh of w -> B fragment.
__device__ __forceinline__ bf16x8 decode_frag(u32 w, int sh) {
    union { bf16x8 v; u32 u[4]; } c;
    c.u[0] = decode_pair((w >> (sh + 0)) & 0xFu);
    c.u[1] = decode_pair((w >> (sh + 4)) & 0xFu);
    c.u[2] = decode_pair((w >> (sh + 8)) & 0xFu);
    c.u[3] = decode_pair((w >> (sh + 12)) & 0xFu);
    return c.v;
}

__device__ __forceinline__ void async_ld16(const void* g, void* l) {
    __builtin_amdgcn_global_load_lds(
        (const __attribute__((address_space(1))) u32*)g,
        (__attribute__((address_space(3))) u32*)l, 16, 0, 0);
}

// ---- pre-pass 1: X fp32 -> bf16 (row-major) ----
__global__ __launch_bounds__(256) void convert_x(const float* __restrict__ X,
                                                 u16* __restrict__ Xb) {
    int i = (blockIdx.x * 256 + threadIdx.x) * 8;
    float4 a = *(const float4*)(X + i);
    float4 b = *(const float4*)(X + i + 4);
    uint4 q;
    q.x = pack_bf16x2(a.x, a.y);
    q.y = pack_bf16x2(a.z, a.w);
    q.z = pack_bf16x2(b.x, b.y);
    q.w = pack_bf16x2(b.z, b.w);
    *(uint4*)(Xb + i) = q;
}

// ---- pre-pass 2: repack W2 -> dense 2-bit fragment-major (W7) ----
// W7 uint2 idx = (((ngrp*2+nh)*32 + w)*4 + kq)*64 + lane
//  .x u16[ksub] = 8 codes for col = ngrp*128 + nh*64 +      (lane&31),
//                 k = w*128 + kq*32 + ksub*16 + (lane>>5)*8 .. +7
//  .y = same for col +32
__global__ __launch_bounds__(256) void repack_w7(const u32* __restrict__ W2,
                                                 uint2* __restrict__ W7) {
    __shared__ u32 dense[128 * 32];    // 16 KB; dense[col*32 + (j ^ (col&31))]
    const int ngrp = blockIdx.x;       // 64 col-groups of 128
    const int kc   = blockIdx.y;       // 8 k-chunks of 512 codes
    const int t = threadIdx.x;
#pragma unroll
    for (int i = 0; i < 16; ++i) {     // phase 1: coalesced uint4 reads
        int id = t + 256 * i;
        int col = id >> 5, jq = id & 31;
        uint4 wv = *(const uint4*)(W2 + (size_t)(ngrp * 128 + col) * KPACK + kc * 128 + jq * 4);
        dense[col * 32 + (jq ^ (col & 31))] =
            (wv.x & 0xFFu) | ((wv.y & 0xFFu) << 8) | ((wv.z & 0xFFu) << 16) | ((wv.w & 0xFFu) << 24);
    }
    __syncthreads();
    const u16* sp = (const u16*)dense;
#pragma unroll
    for (int p = 0; p < 8; ++p) {      // phase 2: coalesced uint2 writes
        int e = t + 256 * p;           // 0..2047
        int lane = e & 63;
        int kq = (e >> 6) & 3;
        int wloc = (e >> 8) & 3;
        int nh = (e >> 10) & 1;
        int h = lane >> 5;
        int c0 = nh * 64 + (lane & 31), c1 = c0 + 32;
        int j0 = wloc * 8 + kq * 2;
        u32 x0 = sp[((c0 * 32 + (j0 ^ (c0 & 31))) << 1) | h];
        u32 x1 = sp[((c0 * 32 + ((j0 + 1) ^ (c0 & 31))) << 1) | h];
        u32 y0 = sp[((c1 * 32 + (j0 ^ (c1 & 31))) << 1) | h];
        u32 y1 = sp[((c1 * 32 + ((j0 + 1) ^ (c1 & 31))) << 1) | h];
        uint2 o;
        o.x = x0 | (x1 << 16);
        o.y = y0 | (y1 << 16);
        int w = kc * 4 + wloc;
        W7[(((size_t)(ngrp * 2 + nh) * 32 + w) * 4 + kq) * 64 + lane] = o;
    }
}

// ---- main GEMM: 64m x 128n block, 8 waves = 4 kq x 2 nh, 32x32x16 MFMA,
//      BK=128 windows, A via DMA-LDS (XOR swizzle), B decoded in-register ----
__global__ __launch_bounds__(512, 4) void ternary_gemm7(
    const u16* __restrict__ Xb,
    const uint2* __restrict__ W7,
    const float* __restrict__ alpha,
    const float* __restrict__ bias,
    float* __restrict__ Out)
{
    __shared__ u16 As[2][TM * BKW];    // 2 x 16 KB; epilogue reuses as reduction scratch

    const int tid  = threadIdx.x;
    const int lane = tid & 63;
    const int wave = tid >> 6;
    const int kq = wave & 3;           // k-quarter (32 of each 128-k window)
    const int nh = wave >> 2;          // n-half (64 cols)

    const int id = blockIdx.x;
    const int m0 = (id & 7) * TM;      // XCD swizzle: all blocks on an XCD share m-tile
    const int ngrp = id >> 3;
    const int n0 = ngrp * TN;

    f32x16 acc[2][2];
#pragma unroll
    for (int mt = 0; mt < 2; ++mt)
#pragma unroll
        for (int nt = 0; nt < 2; ++nt)
#pragma unroll
            for (int i = 0; i < 16; ++i)
                acc[mt][nt][i] = 0.f;

    // DMA: wave stages rows [wave*8, wave*8+8), 2 insts x 4 rows (16 lanes/row).
    // LDS chunk c of row r stored at slot c ^ (r&15); lane writes slot (lane&15).
    const u16* ga[2];
    u32 lbase[2];
#pragma unroll
    for (int i = 0; i < 2; ++i) {
        int rbase = wave * 8 + i * 4;
        int row = rbase + (lane >> 4);
        int cd = (lane & 15) ^ (row & 15);
        ga[i] = Xb + (size_t)(m0 + row) * IN_F + cd * 8;
        lbase[i] = rbase * BKW;
    }

    // A-fragment LDS offsets (u16 units)
    int ofsA[2][2];
#pragma unroll
    for (int mt = 0; mt < 2; ++mt)
#pragma unroll
        for (int ks = 0; ks < 2; ++ks) {
            int row = mt * 32 + (lane & 31);
            int chunk = kq * 4 + ks * 2 + (lane >> 5);
            ofsA[mt][ks] = row * BKW + (chunk ^ (row & 15)) * 8;
        }

    const uint2* wp = W7 + ((size_t)(ngrp * 2 + nh) * NWIN * 4 + kq) * 64 + lane;

    uint2 wcur = wp[0];
    uint2 wnext = wp[256];
#pragma unroll
    for (int i = 0; i < 2; ++i) async_ld16(ga[i], &As[0][lbase[i]]);
    __syncthreads();

    for (int w = 0; w < NWIN; ++w) {
        const int buf = w & 1;
        if (w + 1 < NWIN) {
            const int koff = (w + 1) * BKW;
#pragma unroll
            for (int i = 0; i < 2; ++i)
                async_ld16(ga[i] + koff, &As[buf ^ 1][lbase[i]]);
        }
        uint2 wnn = make_uint2(0, 0);
        if (w + 2 < NWIN) wnn = wp[(size_t)(w + 2) * 256];

        const u16* ab = As[buf];
#pragma unroll
        for (int ks = 0; ks < 2; ++ks) {
            bf16x8 a0 = *(const bf16x8*)(ab + ofsA[0][ks]);
            bf16x8 a1 = *(const bf16x8*)(ab + ofsA[1][ks]);
            bf16x8 b0 = decode_frag(wcur.x, ks * 16);
            bf16x8 b1 = decode_frag(wcur.y, ks * 16);
            acc[0][0] = __builtin_amdgcn_mfma_f32_32x32x16_bf16(a0, b0, acc[0][0], 0, 0, 0);
            acc[1][0] = __builtin_amdgcn_mfma_f32_32x32x16_bf16(a1, b0, acc[1][0], 0, 0, 0);
            acc[0][1] = __builtin_amdgcn_mfma_f32_32x32x16_bf16(a0, b1, acc[0][1], 0, 0, 0);
            acc[1][1] = __builtin_amdgcn_mfma_f32_32x32x16_bf16(a1, b1, acc[1][1], 0, 0, 0);
        }
        wcur = wnext;
        wnext = wnn;
        __syncthreads();
    }

    // ---- 4-way kq reduction through LDS (3 staggered rounds, 32 KB scratch) ----
    f32x4* red = (f32x4*)As;           // 2048 f32x4
#pragma unroll 1
    for (int q = 1; q < 4; ++q) {
        if (kq == q) {
            f32x4* dst = red + nh * 1024 + lane;
#pragma unroll
            for (int mt = 0; mt < 2; ++mt)
#pragma unroll
                for (int nt = 0; nt < 2; ++nt)
#pragma unroll
                    for (int sub = 0; sub < 4; ++sub) {
                        f32x4 v = {acc[mt][nt][sub * 4 + 0], acc[mt][nt][sub * 4 + 1],
                                   acc[mt][nt][sub * 4 + 2], acc[mt][nt][sub * 4 + 3]};
                        dst[((mt * 2 + nt) * 4 + sub) * 64] = v;
                    }
        }
        __syncthreads();
        if (kq == 0) {
            const f32x4* src = red + nh * 1024 + lane;
#pragma unroll
            for (int mt = 0; mt < 2; ++mt)
#pragma unroll
                for (int nt = 0; nt < 2; ++nt)
#pragma unroll
                    for (int sub = 0; sub < 4; ++sub) {
                        f32x4 v = src[((mt * 2 + nt) * 4 + sub) * 64];
#pragma unroll
                        for (int i = 0; i < 4; ++i)
                            acc[mt][nt][sub * 4 + i] += v[i];
                    }
        }
        __syncthreads();
    }

    // ---- epilogue (kq==0 waves): alpha*acc + bias ----
    if (kq == 0) {
#pragma unroll
        for (int nt = 0; nt < 2; ++nt) {
            int ncol = n0 + nh * 64 + nt * 32 + (lane & 31);
            float av = alpha[ncol];
            float bv = bias[ncol];
#pragma unroll
            for (int mt = 0; mt < 2; ++mt) {
#pragma unroll
                for (int r = 0; r < 16; ++r) {
                    int row = m0 + mt * 32 + (r & 3) + 8 * (r >> 2) + 4 * (lane >> 5);
                    Out[(size_t)row * OUT_F + ncol] = acc[mt][nt][r] * av + bv;
                }
            }
        }
    }
}

// ---- naive fallback (workspace too small; correctness only) ----
__global__ void ternary_naive(const float* __restrict__ X, const u32* __restrict__ W2,
                              const float* __restrict__ alpha, const float* __restrict__ bias,
                              float* __restrict__ Out) {
    int o  = blockIdx.x * 64 + (threadIdx.x & 63);
    int tk = blockIdx.y * 4 + (threadIdx.x >> 6);
    const float* x = X + (size_t)tk * IN_F;
    const u32* w = W2 + (size_t)o * KPACK;
    float s = 0.f;
    for (int d = 0; d < KPACK; ++d) {
        u32 b = w[d] & 0xFFu;
        const float* xp = x + d * 4;
#pragma unroll
        for (int j = 0; j < 4; ++j) {
            u32 c = (b >> (2 * j)) & 3u;
            float wv = (c == 2u) ? 1.f : ((c == 0u) ? -1.f : 0.f);
            s += xp[j] * wv;
        }
    }
    Out[(size_t)tk * OUT_F + o] = s * alpha[o] + bias[o];
}

extern "C" void kernel_launch(void* const* d_in, const int* in_sizes, int n_in,
                              void* d_out, int out_size, void* d_ws, size_t ws_size,
                              hipStream_t stream) {
    const float* x = (const float*)d_in[0];
    const u32* w2 = (const u32*)d_in[1];
    const float* alpha = (const float*)d_in[2];
    const float* bias  = (const float*)d_in[3];
    float* out = (float*)d_out;

    const size_t xb_bytes = (size_t)TOKENS * IN_F * sizeof(u16);   // 4 MB
    const size_t w7_bytes = (size_t)OUT_F * IN_F / 4;              // 8 MB

    if (ws_size >= xb_bytes + w7_bytes) {
        u16* xb = (u16*)d_ws;
        uint2* w7 = (uint2*)((char*)d_ws + xb_bytes);
        convert_x<<<(TOKENS * IN_F) / (256 * 8), 256, 0, stream>>>(x, xb);
        repack_w7<<<dim3(64, 8), 256, 0, stream>>>(w2, w7);
        ternary_gemm7<<<512, 512, 0, stream>>>(xb, w7, alpha, bias, out);
    } else {
        ternary_naive<<<dim3(OUT_F / 64, TOKENS / 4), 256, 0, stream>>>(x, w2, alpha, bias, out);
    }
}

// Round 8
// 129.268 us; speedup vs baseline: 1.9583x; 1.0194x over previous
//
#include <hip/hip_runtime.h>
#include <hip/hip_bf16.h>

typedef unsigned int u32;
typedef unsigned short u16;

#define TOKENS 512
#define OUT_F  8192
#define IN_F   4096
#define KPACK  (IN_F / 4)
#define TMB 128              // block m-tile
#define TNB 128              // block n-tile
#define BKW 128              // k per window
#define NWIN (IN_F / BKW)    // 32

typedef __attribute__((ext_vector_type(8))) short bf16x8;
typedef __attribute__((ext_vector_type(4))) float f32x4;
typedef __attribute__((ext_vector_type(16))) float f32x16;

__device__ __forceinline__ u32 pack_bf16x2(float a, float b) {
    __hip_bfloat162 h = __float22bfloat162_rn(make_float2(a, b));
    union { __hip_bfloat162 h2; u32 u; } cvt;
    cvt.h2 = h;
    return cvt.u;
}

// 2 codes (4 bits) -> 2 packed bf16 via byte-table v_perm.
// code 0 -> 0xBF80 (-1), 2 -> 0x3F80 (+1), 1/3 -> 0x0000.
__device__ __forceinline__ u32 decode_pair(u32 d) {
    u32 s = (__umul24(d, 0x808202u) & 0x06060606u) + 0x01000100u;
    return __builtin_amdgcn_perm(0x00003F80u, 0x0000BF80u, s);
}
// 16 bits (8 consecutive-k codes) at bit offset sh of w -> B fragment.
__device__ __forceinline__ bf16x8 decode_frag(u32 w, int sh) {
    union { bf16x8 v; u32 u[4]; } c;
    c.u[0] = decode_pair((w >> (sh + 0)) & 0xFu);
    c.u[1] = decode_pair((w >> (sh + 4)) & 0xFu);
    c.u[2] = decode_pair((w >> (sh + 8)) & 0xFu);
    c.u[3] = decode_pair((w >> (sh + 12)) & 0xFu);
    return c.v;
}

__device__ __forceinline__ void async_ld16(const void* g, void* l) {
    __builtin_amdgcn_global_load_lds(
        (const __attribute__((address_space(1))) u32*)g,
        (__attribute__((address_space(3))) u32*)l, 16, 0, 0);
}

// ---- pre-pass 1: X fp32 -> bf16 (row-major) ----
__global__ __launch_bounds__(256) void convert_x(const float* __restrict__ X,
                                                 u16* __restrict__ Xb) {
    int i = (blockIdx.x * 256 + threadIdx.x) * 8;
    float4 a = *(const float4*)(X + i);
    float4 b = *(const float4*)(X + i + 4);
    uint4 q;
    q.x = pack_bf16x2(a.x, a.y);
    q.y = pack_bf16x2(a.z, a.w);
    q.z = pack_bf16x2(b.x, b.y);
    q.w = pack_bf16x2(b.z, b.w);
    *(uint4*)(Xb + i) = q;
}

// ---- pre-pass 2: repack W2 -> dense 2-bit fragment-major (W7) — unchanged from R7 ----
// W7 uint2 idx = (((ngrp*2+nh)*32 + w)*4 + kq)*64 + lane
//  .x u16[ksub] = 8 codes for col = ngrp*128 + nh*64 +      (lane&31),
//                 k = w*128 + kq*32 + ksub*16 + (lane>>5)*8 .. +7
//  .y = same for col +32
__global__ __launch_bounds__(256) void repack_w7(const u32* __restrict__ W2,
                                                 uint2* __restrict__ W7) {
    __shared__ u32 dense[128 * 32];    // 16 KB; dense[col*32 + (j ^ (col&31))]
    const int ngrp = blockIdx.x;       // 64 col-groups of 128
    const int kc   = blockIdx.y;       // 8 k-chunks of 512 codes
    const int t = threadIdx.x;
#pragma unroll
    for (int i = 0; i < 16; ++i) {     // phase 1: coalesced uint4 reads
        int id = t + 256 * i;
        int col = id >> 5, jq = id & 31;
        uint4 wv = *(const uint4*)(W2 + (size_t)(ngrp * 128 + col) * KPACK + kc * 128 + jq * 4);
        dense[col * 32 + (jq ^ (col & 31))] =
            (wv.x & 0xFFu) | ((wv.y & 0xFFu) << 8) | ((wv.z & 0xFFu) << 16) | ((wv.w & 0xFFu) << 24);
    }
    __syncthreads();
    const u16* sp = (const u16*)dense;
#pragma unroll
    for (int p = 0; p < 8; ++p) {      // phase 2: coalesced uint2 writes
        int e = t + 256 * p;           // 0..2047
        int lane = e & 63;
        int kq = (e >> 6) & 3;
        int wloc = (e >> 8) & 3;
        int nh = (e >> 10) & 1;
        int h = lane >> 5;
        int c0 = nh * 64 + (lane & 31), c1 = c0 + 32;
        int j0 = wloc * 8 + kq * 2;
        u32 x0 = sp[((c0 * 32 + (j0 ^ (c0 & 31))) << 1) | h];
        u32 x1 = sp[((c0 * 32 + ((j0 + 1) ^ (c0 & 31))) << 1) | h];
        u32 y0 = sp[((c1 * 32 + (j0 ^ (c1 & 31))) << 1) | h];
        u32 y1 = sp[((c1 * 32 + ((j0 + 1) ^ (c1 & 31))) << 1) | h];
        uint2 o;
        o.x = x0 | (x1 << 16);
        o.y = y0 | (y1 << 16);
        int w = kc * 4 + wloc;
        W7[(((size_t)(ngrp * 2 + nh) * 32 + w) * 4 + kq) * 64 + lane] = o;
    }
}

// ---- main GEMM: 128x128 block, 512 thr, 8 waves = 4 kq x 2 nh, mt=4,
//      BK=128 windows, 1 block/CU, A via DMA-LDS (XOR swizzle) ----
__global__ __launch_bounds__(512, 2) void ternary_gemm8(
    const u16* __restrict__ Xb,
    const uint2* __restrict__ W7,
    const float* __restrict__ alpha,
    const float* __restrict__ bias,
    float* __restrict__ Out)
{
    __shared__ u16 As[2][TMB * BKW];   // 2 x 32 KB; epilogue reuses as reduction scratch

    const int tid  = threadIdx.x;
    const int lane = tid & 63;
    const int wave = tid >> 6;
    const int kq = wave & 3;           // k-quarter (32 of each 128-k window)
    const int nh = wave >> 2;          // n-half (64 cols)

    const int m0 = blockIdx.x * TMB;   // 4 m-tiles; XCD-local via round-robin dispatch
    const int ngrp = blockIdx.y;
    const int n0 = ngrp * TNB;

    f32x16 acc[4][2];
#pragma unroll
    for (int mt = 0; mt < 4; ++mt)
#pragma unroll
        for (int nt = 0; nt < 2; ++nt)
#pragma unroll
            for (int i = 0; i < 16; ++i)
                acc[mt][nt][i] = 0.f;

    // DMA staging: wave stages rows [wave*16, wave*16+16), 4 insts x 4 rows.
    // Row = 128 k = 16 chunks of 16 B; chunk c stored at slot c ^ (row&15).
    const u16* ga[4];
    u32 lbase[4];
#pragma unroll
    for (int i = 0; i < 4; ++i) {
        int rbase = wave * 16 + i * 4;
        int row = rbase + (lane >> 4);
        int cd = (lane & 15) ^ (row & 15);
        ga[i] = Xb + (size_t)(m0 + row) * IN_F + cd * 8;
        lbase[i] = rbase * BKW;
    }

    // A-fragment LDS offsets (u16 units); row&15 == lane&15 since mt*32 ≡ 0 mod 16
    int ofsA[4][2];
#pragma unroll
    for (int mt = 0; mt < 4; ++mt)
#pragma unroll
        for (int ks = 0; ks < 2; ++ks) {
            int row = mt * 32 + (lane & 31);
            int chunk = kq * 4 + ks * 2 + (lane >> 5);
            ofsA[mt][ks] = row * BKW + ((chunk ^ (row & 15))) * 8;
        }

    const uint2* wp = W7 + ((size_t)(ngrp * 2 + nh) * NWIN * 4 + kq) * 64 + lane;

    uint2 wcur = wp[0];
    uint2 wnext = wp[256];
#pragma unroll
    for (int i = 0; i < 4; ++i) async_ld16(ga[i], &As[0][lbase[i]]);
    __syncthreads();

    for (int w = 0; w < NWIN; ++w) {
        const int buf = w & 1;
        if (w + 1 < NWIN) {
            const int koff = (w + 1) * BKW;
#pragma unroll
            for (int i = 0; i < 4; ++i)
                async_ld16(ga[i] + koff, &As[buf ^ 1][lbase[i]]);
        }
        uint2 wnn = make_uint2(0, 0);
        if (w + 2 < NWIN) wnn = wp[(size_t)(w + 2) * 256];

        const u16* ab = As[buf];
#pragma unroll
        for (int ks = 0; ks < 2; ++ks) {
            bf16x8 a0 = *(const bf16x8*)(ab + ofsA[0][ks]);
            bf16x8 a1 = *(const bf16x8*)(ab + ofsA[1][ks]);
            bf16x8 a2 = *(const bf16x8*)(ab + ofsA[2][ks]);
            bf16x8 a3 = *(const bf16x8*)(ab + ofsA[3][ks]);
            bf16x8 b0 = decode_frag(wcur.x, ks * 16);
            bf16x8 b1 = decode_frag(wcur.y, ks * 16);
            acc[0][0] = __builtin_amdgcn_mfma_f32_32x32x16_bf16(a0, b0, acc[0][0], 0, 0, 0);
            acc[1][0] = __builtin_amdgcn_mfma_f32_32x32x16_bf16(a1, b0, acc[1][0], 0, 0, 0);
            acc[2][0] = __builtin_amdgcn_mfma_f32_32x32x16_bf16(a2, b0, acc[2][0], 0, 0, 0);
            acc[3][0] = __builtin_amdgcn_mfma_f32_32x32x16_bf16(a3, b0, acc[3][0], 0, 0, 0);
            acc[0][1] = __builtin_amdgcn_mfma_f32_32x32x16_bf16(a0, b1, acc[0][1], 0, 0, 0);
            acc[1][1] = __builtin_amdgcn_mfma_f32_32x32x16_bf16(a1, b1, acc[1][1], 0, 0, 0);
            acc[2][1] = __builtin_amdgcn_mfma_f32_32x32x16_bf16(a2, b1, acc[2][1], 0, 0, 0);
            acc[3][1] = __builtin_amdgcn_mfma_f32_32x32x16_bf16(a3, b1, acc[3][1], 0, 0, 0);
        }
        wcur = wnext;
        wnext = wnn;
        __syncthreads();
    }

    // ---- 4-way kq reduction through LDS (3 staggered rounds, 64 KB scratch) ----
    f32x4* red = (f32x4*)As;           // 4096 f32x4 = 64 KB
#pragma unroll 1
    for (int q = 1; q < 4; ++q) {
        if (kq == q) {
            f32x4* dst = red + nh * 2048 + lane;
#pragma unroll
            for (int mt = 0; mt < 4; ++mt)
#pragma unroll
                for (int nt = 0; nt < 2; ++nt)
#pragma unroll
                    for (int sub = 0; sub < 4; ++sub) {
                        f32x4 v = {acc[mt][nt][sub * 4 + 0], acc[mt][nt][sub * 4 + 1],
                                   acc[mt][nt][sub * 4 + 2], acc[mt][nt][sub * 4 + 3]};
                        dst[(mt * 8 + nt * 4 + sub) * 64] = v;
                    }
        }
        __syncthreads();
        if (kq == 0) {
            const f32x4* src = red + nh * 2048 + lane;
#pragma unroll
            for (int mt = 0; mt < 4; ++mt)
#pragma unroll
                for (int nt = 0; nt < 2; ++nt)
#pragma unroll
                    for (int sub = 0; sub < 4; ++sub) {
                        f32x4 v = src[(mt * 8 + nt * 4 + sub) * 64];
#pragma unroll
                        for (int i = 0; i < 4; ++i)
                            acc[mt][nt][sub * 4 + i] += v[i];
                    }
        }
        __syncthreads();
    }

    // ---- epilogue (kq==0 waves): alpha*acc + bias ----
    if (kq == 0) {
#pragma unroll
        for (int nt = 0; nt < 2; ++nt) {
            int ncol = n0 + nh * 64 + nt * 32 + (lane & 31);
            float av = alpha[ncol];
            float bv = bias[ncol];
#pragma unroll
            for (int mt = 0; mt < 4; ++mt) {
#pragma unroll
                for (int r = 0; r < 16; ++r) {
                    int row = m0 + mt * 32 + (r & 3) + 8 * (r >> 2) + 4 * (lane >> 5);
                    Out[(size_t)row * OUT_F + ncol] = acc[mt][nt][r] * av + bv;
                }
            }
        }
    }
}

// ---- naive fallback (workspace too small; correctness only) ----
__global__ void ternary_naive(const float* __restrict__ X, const u32* __restrict__ W2,
                              const float* __restrict__ alpha, const float* __restrict__ bias,
                              float* __restrict__ Out) {
    int o  = blockIdx.x * 64 + (threadIdx.x & 63);
    int tk = blockIdx.y * 4 + (threadIdx.x >> 6);
    const float* x = X + (size_t)tk * IN_F;
    const u32* w = W2 + (size_t)o * KPACK;
    float s = 0.f;
    for (int d = 0; d < KPACK; ++d) {
        u32 b = w[d] & 0xFFu;
        const float* xp = x + d * 4;
#pragma unroll
        for (int j = 0; j < 4; ++j) {
            u32 c = (b >> (2 * j)) & 3u;
            float wv = (c == 2u) ? 1.f : ((c == 0u) ? -1.f : 0.f);
            s += xp[j] * wv;
        }
    }
    Out[(size_t)tk * OUT_F + o] = s * alpha[o] + bias[o];
}

extern "C" void kernel_launch(void* const* d_in, const int* in_sizes, int n_in,
                              void* d_out, int out_size, void* d_ws, size_t ws_size,
                              hipStream_t stream) {
    const float* x = (const float*)d_in[0];
    const u32* w2 = (const u32*)d_in[1];
    const float* alpha = (const float*)d_in[2];
    const float* bias  = (const float*)d_in[3];
    float* out = (float*)d_out;

    const size_t xb_bytes = (size_t)TOKENS * IN_F * sizeof(u16);   // 4 MB
    const size_t w7_bytes = (size_t)OUT_F * IN_F / 4;              // 8 MB

    if (ws_size >= xb_bytes + w7_bytes) {
        u16* xb = (u16*)d_ws;
        uint2* w7 = (uint2*)((char*)d_ws + xb_bytes);
        convert_x<<<(TOKENS * IN_F) / (256 * 8), 256, 0, stream>>>(x, xb);
        repack_w7<<<dim3(64, 8), 256, 0, stream>>>(w2, w7);
        ternary_gemm8<<<dim3(TOKENS / TMB, OUT_F / TNB), 512, 0, stream>>>(xb, w7, alpha, bias, out);
    } else {
        ternary_naive<<<dim3(OUT_F / 64, TOKENS / 4), 256, 0, stream>>>(x, w2, alpha, bias, out);
    }
}